// Round 9
// baseline (257.345 us; speedup 1.0000x reference)
//
#include <hip/hip_runtime.h>
#include <hip/hip_bf16.h>

// MHA forward: B=2, H=16, S=2048, D=1024, d_k=64, causal, RoPE(theta=1e4)
// R8 -> R9:
//  - attn: grid 1024 (ONE 64-row q-tile per block, interleaved heavy/light order)
//          -> 4 blocks/CU (16 waves/CU, was 8); exp2 softmax (Q pre-scaled by
//          0.125*log2e in fp32 at RoPE); s_setprio(1) around MFMA clusters.
//          DMA dbuf staging + XOR swizzle + defer-max + per-lane l kept.
//  - cvt: x + 4 weights in ONE dispatch.
//  - gemm: unchanged structure + __launch_bounds__(256,2) VGPR guard.

typedef __bf16 bf16x8 __attribute__((ext_vector_type(8)));
typedef __bf16 bf16x4 __attribute__((ext_vector_type(4)));
typedef float f32x4 __attribute__((ext_vector_type(4)));
typedef unsigned short ushort8 __attribute__((ext_vector_type(8)));

#define BATCH 2
#define SEQ 2048
#define NH 16
#define DK 64
#define DM 1024
#define BH (BATCH*NH)
#define M_TOT (BATCH*SEQ)   // 4096
#define NX (M_TOT*DM)       // 4194304
#define NW (DM*DM)          // 1048576 = 1<<20

__device__ __forceinline__ void gload16(const void* g, void* l) {
    // async global->LDS, 16B/lane; LDS dest = wave-uniform base + lane*16
    __builtin_amdgcn_global_load_lds((const __attribute__((address_space(1))) void*)g,
                                     (__attribute__((address_space(3))) void*)l, 16, 0, 0);
}

// ---------------- fp32 -> bf16 convert: x + Wq,Wk,Wv,Wo in one dispatch ----------------
__global__ void cvt_all(const float* __restrict__ x,
                        const float* __restrict__ Wq, const float* __restrict__ Wk,
                        const float* __restrict__ Wv, const float* __restrict__ Wo,
                        __bf16* __restrict__ xb, __bf16* __restrict__ wqkv,
                        __bf16* __restrict__ wob) {
    int i4 = (blockIdx.x * blockDim.x + threadIdx.x) * 4;
    const float* s;
    __bf16* d;
    int off;
    if (i4 < NX) { s = x; d = xb; off = i4; }
    else {
        int j = i4 - NX;
        int z = j >> 20;
        off = j & (NW - 1);
        s = (z == 0) ? Wq : (z == 1) ? Wk : (z == 2) ? Wv : Wo;
        d = (z == 3) ? wob : wqkv + (size_t)z * NW;
    }
    float4 v = *(const float4*)(s + off);
    bf16x4 o;
    o[0] = (__bf16)v.x; o[1] = (__bf16)v.y; o[2] = (__bf16)v.z; o[3] = (__bf16)v.w;
    *(bf16x4*)(d + off) = o;
}

// ---------------- GEMM core (R5/R6 proven): BK=32, linear [128][32] LDS ----------------
__device__ __forceinline__ void gemm_tile_compute(
    const __bf16* __restrict__ A, const __bf16* __restrict__ W,
    int m0, int n0, int K, __bf16* sA, __bf16* sB, f32x4 (&acc)[4][4])
{
    const int t = threadIdx.x;
    const int lane = t & 63, wid = t >> 6;
    const int wr = wid >> 1, wc = wid & 1;
    const int g = lane >> 4, l15 = lane & 15;

    f32x4 zero = {0.f, 0.f, 0.f, 0.f};
#pragma unroll
    for (int mt = 0; mt < 4; ++mt)
#pragma unroll
        for (int nt = 0; nt < 4; ++nt) acc[mt][nt] = zero;

    for (int k0 = 0; k0 < K; k0 += 32) {
        __syncthreads();
#pragma unroll
        for (int rnd = 0; rnd < 2; ++rnd) {
            int s = rnd * 256 + t;
            int row = s >> 2, ch = s & 3;
            __bf16* dstA = sA + (rnd * 256 + wid * 64) * 8;
            __bf16* dstB = sB + (rnd * 256 + wid * 64) * 8;
            gload16(A + (size_t)(m0 + row) * K + k0 + ch * 8, dstA);
            gload16(W + (size_t)(n0 + row) * K + k0 + ch * 8, dstB);
        }
        __syncthreads();
        bf16x8 af[4], bfr[4];
#pragma unroll
        for (int mt = 0; mt < 4; ++mt)
            af[mt] = *(const bf16x8*)&sA[(wr * 64 + mt * 16 + l15) * 32 + g * 8];
#pragma unroll
        for (int nt = 0; nt < 4; ++nt)
            bfr[nt] = *(const bf16x8*)&sB[(wc * 64 + nt * 16 + l15) * 32 + g * 8];
#pragma unroll
        for (int mt = 0; mt < 4; ++mt)
#pragma unroll
            for (int nt = 0; nt < 4; ++nt)
                acc[mt][nt] = __builtin_amdgcn_mfma_f32_16x16x32_bf16(af[mt], bfr[nt], acc[mt][nt], 0, 0, 0);
    }
}

// Merged QKV GEMM: W = [Wq;Wk;Wv] rows 0..3071. Q/K [B,H,S,dk], V^T [B,H,dk,S].
__global__ __launch_bounds__(256, 2) void gemm_qkv(
    const __bf16* __restrict__ xb, const __bf16* __restrict__ wqkv,
    __bf16* __restrict__ Qb, __bf16* __restrict__ Kb, __bf16* __restrict__ VTb)
{
    __shared__ __align__(16) __bf16 sA[128 * 32], sB[128 * 32];
    int id = blockIdx.x + 24 * blockIdx.y;       // 0..767
    id = (id & 7) * 96 + (id >> 3);              // XCD-contiguous (768%8==0)
    const int m0 = (id / 24) * 128, n0 = (id % 24) * 128;

    f32x4 acc[4][4];
    gemm_tile_compute(xb, wqkv, m0, n0, DM, sA, sB, acc);

    const int t = threadIdx.x, lane = t & 63, wid = t >> 6;
    const int wr = wid >> 1, wc = wid & 1, g = lane >> 4, l15 = lane & 15;
#pragma unroll
    for (int mt = 0; mt < 4; ++mt)
#pragma unroll
        for (int nt = 0; nt < 4; ++nt)
#pragma unroll
            for (int r = 0; r < 4; ++r) {
                int m = m0 + wr * 64 + mt * 16 + g * 4 + r;   // (b, s)
                int n = n0 + wc * 64 + nt * 16 + l15;         // 0..3071
                int z = n >> 10, hd = n & 1023, h = hd >> 6, d = hd & 63;
                int b = m >> 11, s = m & 2047;
                __bf16 v = (__bf16)acc[mt][nt][r];
                if (z == 0)
                    Qb[(((size_t)(b * NH + h)) * SEQ + s) * DK + d] = v;
                else if (z == 1)
                    Kb[(((size_t)(b * NH + h)) * SEQ + s) * DK + d] = v;
                else
                    VTb[(((size_t)(b * NH + h)) * DK + d) * SEQ + s] = v;
            }
}

// Output GEMM: out[M,1024] fp32 = AO[M,1024]bf16 @ Wo^T
__global__ __launch_bounds__(256, 2) void gemm_out(
    const __bf16* __restrict__ AO, const __bf16* __restrict__ wo, float* __restrict__ out)
{
    __shared__ __align__(16) __bf16 sA[128 * 32], sB[128 * 32];
    int id = blockIdx.x + 8 * blockIdx.y;        // 0..255
    id = (id & 7) * 32 + (id >> 3);              // XCD-contiguous
    const int m0 = (id / 8) * 128, n0 = (id % 8) * 128;

    f32x4 acc[4][4];
    gemm_tile_compute(AO, wo, m0, n0, DM, sA, sB, acc);

    const int t = threadIdx.x, lane = t & 63, wid = t >> 6;
    const int wr = wid >> 1, wc = wid & 1, g = lane >> 4, l15 = lane & 15;
#pragma unroll
    for (int mt = 0; mt < 4; ++mt)
#pragma unroll
        for (int nt = 0; nt < 4; ++nt)
#pragma unroll
            for (int r = 0; r < 4; ++r) {
                int m = m0 + wr * 64 + mt * 16 + g * 4 + r;
                int n = n0 + wc * 64 + nt * 16 + l15;
                out[(size_t)m * DM + n] = acc[mt][nt][r];
            }
}

// ---------------- RoPE (in-place; Q scaled by 0.125*log2(e) in fp32) ----------------
__global__ __launch_bounds__(256) void rope_kernel(
    __bf16* __restrict__ Qb, __bf16* __restrict__ Kb, const int* __restrict__ pos)
{
    __shared__ float ctab[32], stab[32];
    const int s = blockIdx.x;
    const int t = threadIdx.x;
    if (t < 32) {
        float invf = exp2f(-13.287712379549449f * (float)t * (1.0f / 32.0f));
        float ang = (float)pos[s] * invf;
        float sn, cs;
        sincosf(ang, &sn, &cs);
        ctab[t] = cs; stab[t] = sn;
    }
    __syncthreads();
#pragma unroll
    for (int u = 0; u < 8; ++u) {
        int id = u * 256 + t;
        int i = id & 31;
        int bh = (id >> 5) & 31;
        int isK = id >> 10;
        __bf16* P = isK ? Kb : Qb;
        // fold 1/sqrt(dk) * log2(e) into Q (fp32 mul before bf16 cast -> no extra error)
        float qs = isK ? 1.0f : (0.125f * 1.44269504088896f);
        __bf16* p = P + ((size_t)bh * SEQ + s) * DK + i * 2;
        float x1 = (float)p[0], x2 = (float)p[1];
        float c = ctab[i], sn = stab[i];
        p[0] = (__bf16)(qs * (x1 * c - x2 * sn));
        p[1] = (__bf16)(qs * (x1 * sn + x2 * c));
    }
}

// ---------------- Flash attention ----------------
// grid 1024: xcd = n&7, slot = n>>3 (0..127): bh = xcd*4 + (slot>>5), js = slot&31,
// j = interleaved heavy/light so co-scheduled blocks are ~balanced.
// 4 blocks/CU co-resident (LDS 40KB, VGPR ~80) -> 16 waves/CU.
// Block: 4 waves x 16 q-rows; K/V dbuf DMA-staged (linear dest, inv-swizzled src).
// Softmax in log2 domain (Q pre-scaled); defer-max THR=11.54 (=8*log2e).
__global__ __launch_bounds__(256, 2) void attn_kernel(
    const __bf16* __restrict__ Qb, const __bf16* __restrict__ Kb,
    const __bf16* __restrict__ VTb, __bf16* __restrict__ AO)
{
    __shared__ __align__(16) __bf16 sK[2][64 * 64];       // [buf][kv][d] swizzled
    __shared__ __align__(16) __bf16 sV[2][64 * 64];       // [buf][d][kv] swizzled
    __shared__ __align__(16) __bf16 sP[4 * 16 * 64];      // [wave][16 q][64 kv] swizzled

    const int n = blockIdx.x;                  // 0..1023
    const int xcd = n & 7, slot = n >> 3;      // 128 slots per XCD
    const int bh = xcd * 4 + (slot >> 5);
    const int js = slot & 31;
    const int j = (js & 1) ? (js >> 1) : (31 - (js >> 1));   // interleaved order
    const int t = threadIdx.x, lane = t & 63, wid = t >> 6;
    const int g = lane >> 4, l15 = lane & 15;

    const size_t baseQK = (size_t)bh * SEQ * DK;
    const size_t baseVT = (size_t)bh * DK * SEQ;
    const int b = bh >> 4, h = bh & 15;
    const int qrow_w = j * 64 + wid * 16;      // wave's q rows
    const int ktmax = j;

    const char* Kt0 = (const char*)(Kb + baseQK);
    const char* Vt0 = (const char*)(VTb + baseVT);
    char* myP = (char*)sP + wid * 2048;
    f32x4 zero = {0.f, 0.f, 0.f, 0.f};

    auto stage_tile = [&](int kt, int bq) {
        const char* Kt = Kt0 + (size_t)kt * 64 * 128;
        const char* Vt = Vt0 + (size_t)kt * 128;
#pragma unroll
        for (int cc = 0; cc < 2; ++cc) {
            int c = t + cc * 256;
            int r = c >> 3, pp = c & 7;
            int p = pp ^ (r & 7);              // involution: source chunk
            char* bK = (char*)sK[bq] + (cc * 256 + wid * 64) * 16;
            char* bV = (char*)sV[bq] + (cc * 256 + wid * 64) * 16;
            gload16(Kt + (size_t)r * 128 + p * 16, bK);
            gload16(Vt + (size_t)r * (SEQ * 2) + p * 16, bV);
        }
    };

    stage_tile(0, 0);                          // DMA in flight during Q loads

    // Q fragments (pre-scaled by 0.125*log2e in RoPE)
    bf16x8 qf[2];
    {
        const __bf16* qp = Qb + baseQK + (size_t)(qrow_w + l15) * DK;
        qf[0] = *(const bf16x8*)(qp + g * 8);
        qf[1] = *(const bf16x8*)(qp + 32 + g * 8);
    }

    f32x4 oacc[4];
    float mrow[4], lacc[4];
#pragma unroll
    for (int dt = 0; dt < 4; ++dt) oacc[dt] = zero;
#pragma unroll
    for (int r = 0; r < 4; ++r) { mrow[r] = -3e38f; lacc[r] = 0.f; }

    __syncthreads();                           // buf0 valid
    int cur = 0;

    for (int kt = 0; kt <= ktmax; ++kt) {
        if (kt < ktmax) stage_tile(kt + 1, cur ^ 1);   // DMA overlaps compute

        // ---- S = Q K^T (log2-domain, pre-scaled) ----
        f32x4 sacc[4];
        __builtin_amdgcn_s_setprio(1);
#pragma unroll
        for (int nt = 0; nt < 4; ++nt) {
            sacc[nt] = zero;
            int row = nt * 16 + l15;
#pragma unroll
            for (int ks = 0; ks < 2; ++ks) {
                bf16x8 kf = *(const bf16x8*)((const char*)sK[cur] + row * 128 +
                                             ((ks * 64 + g * 16) ^ ((row & 7) << 4)));
                sacc[nt] = __builtin_amdgcn_mfma_f32_16x16x32_bf16(qf[ks], kf, sacc[nt], 0, 0, 0);
            }
        }
        __builtin_amdgcn_s_setprio(0);

        // ---- causal mask: only the diagonal tile ----
        if (kt == ktmax) {
#pragma unroll
            for (int nt = 0; nt < 4; ++nt)
#pragma unroll
                for (int r = 0; r < 4; ++r) {
                    int kv = kt * 64 + nt * 16 + l15;
                    int q = qrow_w + g * 4 + r;
                    if (kv > q) sacc[nt][r] = -3e38f;
                }
        }

        // ---- online softmax (log2 domain), defer-max, per-lane l ----
#pragma unroll
        for (int r = 0; r < 4; ++r) {
            float tm = fmaxf(fmaxf(sacc[0][r], sacc[1][r]), fmaxf(sacc[2][r], sacc[3][r]));
#pragma unroll
            for (int msk = 1; msk < 16; msk <<= 1) tm = fmaxf(tm, __shfl_xor(tm, msk));
            if (tm > mrow[r] + 11.5416f) {     // rare rescale (P bounded by 2^11.54 = e^8)
                float sc = exp2f(mrow[r] - tm);
                mrow[r] = tm;
                lacc[r] *= sc;
#pragma unroll
                for (int dt = 0; dt < 4; ++dt) oacc[dt][r] *= sc;
            }
#pragma unroll
            for (int nt = 0; nt < 4; ++nt) {
                float p = exp2f(sacc[nt][r] - mrow[r]);
                sacc[nt][r] = p;
                lacc[r] += p;
            }
        }

        // ---- P -> per-wave LDS (swizzled); same-wave DS in-order ----
#pragma unroll
        for (int nt = 0; nt < 4; ++nt)
#pragma unroll
            for (int r = 0; r < 4; ++r) {
                int row = g * 4 + r;
                *(__bf16*)(myP + row * 128 +
                           ((nt * 32 + l15 * 2) ^ ((row & 7) << 4))) = (__bf16)sacc[nt][r];
            }

        // ---- O += P V ----
        __builtin_amdgcn_s_setprio(1);
#pragma unroll
        for (int ks = 0; ks < 2; ++ks) {
            bf16x8 pf = *(const bf16x8*)(myP + l15 * 128 +
                                         ((ks * 64 + g * 16) ^ ((l15 & 7) << 4)));
#pragma unroll
            for (int dt = 0; dt < 4; ++dt) {
                int row = dt * 16 + l15;
                bf16x8 vf = *(const bf16x8*)((const char*)sV[cur] + row * 128 +
                                             ((ks * 64 + g * 16) ^ ((row & 7) << 4)));
                oacc[dt] = __builtin_amdgcn_mfma_f32_16x16x32_bf16(pf, vf, oacc[dt], 0, 0, 0);
            }
        }
        __builtin_amdgcn_s_setprio(0);

        __syncthreads();   // DMA drained (next buf ready) + all waves done with cur
        cur ^= 1;
    }

    // ---- epilogue: reduce l across 16 lanes, O /= l, write AO ----
#pragma unroll
    for (int r = 0; r < 4; ++r) {
        float rs = lacc[r];
#pragma unroll
        for (int msk = 1; msk < 16; msk <<= 1) rs += __shfl_xor(rs, msk);
        float inv = 1.0f / rs;
        int srow = qrow_w + g * 4 + r;
        size_t obase = ((size_t)b * SEQ + srow) * DM + h * DK;
#pragma unroll
        for (int dt = 0; dt < 4; ++dt)
            AO[obase + dt * 16 + l15] = (__bf16)(oacc[dt][r] * inv);
    }
}

// ---------------- launch ----------------
extern "C" void kernel_launch(void* const* d_in, const int* in_sizes, int n_in,
                              void* d_out, int out_size, void* d_ws, size_t ws_size,
                              hipStream_t stream) {
    (void)in_sizes; (void)n_in; (void)out_size; (void)ws_size;
    const float* x  = (const float*)d_in[0];
    const int*  pos = (const int*)d_in[1];
    const float* Wq = (const float*)d_in[2];
    const float* Wk = (const float*)d_in[3];
    const float* Wv = (const float*)d_in[4];
    const float* Wo = (const float*)d_in[5];
    float* out = (float*)d_out;

    char* ws = (char*)d_ws;
    __bf16* xb   = (__bf16*)ws; ws += (size_t)M_TOT * DM * 2;
    __bf16* wqkv = (__bf16*)ws; ws += (size_t)3 * DM * DM * 2;
    __bf16* wob  = (__bf16*)ws; ws += (size_t)DM * DM * 2;
    __bf16* Qb   = (__bf16*)ws; ws += (size_t)BH * SEQ * DK * 2;
    __bf16* Kb   = (__bf16*)ws; ws += (size_t)BH * SEQ * DK * 2;
    __bf16* VTb  = (__bf16*)ws; ws += (size_t)BH * SEQ * DK * 2;
    __bf16* AOb  = (__bf16*)ws; ws += (size_t)M_TOT * DM * 2;

    const int ntot = NX + 4 * NW;
    cvt_all<<<ntot / 4 / 256, 256, 0, stream>>>(x, Wq, Wk, Wv, Wo, xb, wqkv, wob);

    gemm_qkv<<<dim3(24, M_TOT / 128), 256, 0, stream>>>(xb, wqkv, Qb, Kb, VTb);
    rope_kernel<<<SEQ, 256, 0, stream>>>(Qb, Kb, pos);
    attn_kernel<<<1024, 256, 0, stream>>>(Qb, Kb, VTb, AOb);
    gemm_out<<<dim3(8, M_TOT / 128), 256, 0, stream>>>(AOb, wob, out);
}